// Round 5
// baseline (324.351 us; speedup 1.0000x reference)
//
#include <hip/hip_runtime.h>

// SelfAttentionCNN reduced form:
//   M = X^T X (64x64), ST = Wg^T M Wf (8x8), Beta = rowsoftmax(ST),
//   u = Beta^T Wv, w = Gamma * Wh u (64), V_p = w . x_p,
//   out[p][c] = x[p][c] + V[(p & 8191)*64 + c]   (P = 2^19)

#define P_PIX (32 * 128 * 128)   // 524288
#define NGROUP 8192              // P_PIX / 64
#define TILE_P 256
#define NTILE (P_PIX / TILE_P)   // 2048
#define COV_BLOCKS 512

typedef __attribute__((ext_vector_type(8))) short bf16x8;
typedef __attribute__((ext_vector_type(4))) float f32x4;

__device__ __forceinline__ unsigned rne16(unsigned u) {
    return (u + 0x7FFFu + ((u >> 16) & 1u)) >> 16;   // RNE f32->bf16 bits
}
// LDS slot swizzle: bijective on {cbase..cbase+15} (frag reads) AND on
// {4q+e : q=0..15} (staging writes) -> conflict-free both directions.
__device__ __forceinline__ int slotf(int chan) {
    return (((chan >> 2) & 3) << 2) | ((chan ^ (chan >> 4)) & 3);
}

// ---------------- K1: M = X^T X via MFMA (bf16 hi/lo split) ----------------
// 512 blocks x 256 threads, 256-pixel tiles. Transposed LDS tile (hi+lo bf16,
// swizzled). Waves split over K (2 K-steps each), every wave computes the FULL
// 64x64 M from ONE set of 8 frag loads per K-step (A-frag == B-frag data).
// Epilogue: block-reduce 4 wave-partials in LDS, 4096 atomicAdds per block.
__global__ __launch_bounds__(256) void k_cov(const float* __restrict__ x,
                                             float* __restrict__ M) {
    __shared__ __align__(16) char lds[65536];
    char* const xh = lds;                 // [64 chans][512 B of pixels]
    char* const xl = lds + 32768;
    const int t = threadIdx.x;
    const int w = t >> 6;                 // wave 0..3
    const int l = t & 63;

    f32x4 acc[4][4] = {};

    const int sg = t >> 4;                // pixel-octet group 0..15
    const int c0 = (t & 15) * 4;          // chan base for staging

    int woffBase[4];
    #pragma unroll
    for (int e = 0; e < 4; ++e) {
        const int chan = c0 + e;
        woffBase[e] = chan * 512 + 16 * (sg ^ slotf(chan));
    }

    for (int tile = blockIdx.x; tile < NTILE; tile += COV_BLOCKS) {
        __syncthreads();                  // prev tile's frag readers done
        // ---- stage: 2 passes x (8 pixels x 4 chans) per thread ----
        #pragma unroll
        for (int pp = 0; pp < 2; ++pp) {
            const float* src = x +
                ((size_t)(tile * TILE_P + pp * 128 + sg * 8)) * 64 + c0;
            f32x4 v[8];
            #pragma unroll
            for (int r = 0; r < 8; ++r) v[r] = *(const f32x4*)(src + r * 64);
            #pragma unroll
            for (int e = 0; e < 4; ++e) {
                unsigned hp[4], lp[4];
                #pragma unroll
                for (int j = 0; j < 4; ++j) {
                    float a0 = v[2 * j][e], a1 = v[2 * j + 1][e];
                    unsigned u0 = __builtin_bit_cast(unsigned, a0);
                    unsigned u1 = __builtin_bit_cast(unsigned, a1);
                    unsigned h0 = rne16(u0), h1 = rne16(u1);
                    float r0 = a0 - __builtin_bit_cast(float, h0 << 16);
                    float r1 = a1 - __builtin_bit_cast(float, h1 << 16);
                    unsigned l0 = rne16(__builtin_bit_cast(unsigned, r0));
                    unsigned l1 = rne16(__builtin_bit_cast(unsigned, r1));
                    hp[j] = h0 | (h1 << 16);
                    lp[j] = l0 | (l1 << 16);
                }
                const int off = woffBase[e] + 256 * pp;
                *(uint4*)(xh + off) = make_uint4(hp[0], hp[1], hp[2], hp[3]);
                *(uint4*)(xl + off) = make_uint4(lp[0], lp[1], lp[2], lp[3]);
            }
        }
        __syncthreads();
        // ---- MFMA: wave w handles K-steps w and w+4 (32 pixels each) ----
        #pragma unroll
        for (int ks2 = 0; ks2 < 2; ++ks2) {
            const int ks = w + ks2 * 4;
            bf16x8 fh[4], fl[4];
            #pragma unroll
            for (int cb = 0; cb < 4; ++cb) {
                const int chan = cb * 16 + (l & 15);
                const int off = chan * 512 +
                    ((ks * 64 + (l >> 4) * 16) ^ (slotf(chan) << 4));
                fh[cb] = *(const bf16x8*)(xh + off);
                fl[cb] = *(const bf16x8*)(xl + off);
            }
            #pragma unroll
            for (int a = 0; a < 4; ++a)
                #pragma unroll
                for (int b = 0; b < 4; ++b)
                    acc[a][b] = __builtin_amdgcn_mfma_f32_16x16x32_bf16(
                        fh[a], fh[b], acc[a][b], 0, 0, 0);
            #pragma unroll
            for (int a = 0; a < 4; ++a)
                #pragma unroll
                for (int b = 0; b < 4; ++b)
                    acc[a][b] = __builtin_amdgcn_mfma_f32_16x16x32_bf16(
                        fh[a], fl[b], acc[a][b], 0, 0, 0);
            #pragma unroll
            for (int a = 0; a < 4; ++a)
                #pragma unroll
                for (int b = 0; b < 4; ++b)
                    acc[a][b] = __builtin_amdgcn_mfma_f32_16x16x32_bf16(
                        fl[a], fh[b], acc[a][b], 0, 0, 0);
        }
    }

    // ---- epilogue: reduce 4 wave-partials in LDS, then global atomics ----
    __syncthreads();
    float* scr = (float*)lds;             // [w][a4b][lane][r] = 4 x 4096 floats
    #pragma unroll
    for (int a = 0; a < 4; ++a)
        #pragma unroll
        for (int b = 0; b < 4; ++b)
            *(f32x4*)&scr[(((w * 16) + a * 4 + b) * 64 + l) * 4] = acc[a][b];
    __syncthreads();
    #pragma unroll
    for (int j = 0; j < 4; ++j) {
        const int u0 = t * 16 + j * 4;
        f32x4 s = *(const f32x4*)&scr[u0];
        s += *(const f32x4*)&scr[4096 + u0];
        s += *(const f32x4*)&scr[8192 + u0];
        s += *(const f32x4*)&scr[12288 + u0];
        const int a4b = u0 >> 8;
        const int lidx = (u0 >> 2) & 63;
        const int rowb = (a4b >> 2) * 16 + (lidx >> 4) * 4;
        const int col = (a4b & 3) * 16 + (lidx & 15);
        #pragma unroll
        for (int r = 0; r < 4; ++r)
            atomicAdd(&M[(rowb + r) * 64 + col], s[r]);
    }
}

// ---------------- K2: Beta, w ----------------
__global__ __launch_bounds__(64) void k_beta(const float* __restrict__ M,
                                             const float* __restrict__ Wf,
                                             const float* __restrict__ Wg,
                                             const float* __restrict__ Wh,
                                             const float* __restrict__ Wv,
                                             const float* __restrict__ Gamma,
                                             float* __restrict__ w_out) {
    __shared__ float Tl[64][8];
    __shared__ float STl[64];
    __shared__ float El[64];
    __shared__ float Bl[64];
    __shared__ float ul[8];
    const int t = threadIdx.x;

    float Tr[8] = {};
    for (int b = 0; b < 64; ++b) {
        float m = M[t * 64 + b];
        #pragma unroll
        for (int j = 0; j < 8; ++j) Tr[j] = fmaf(m, Wf[b * 8 + j], Tr[j]);
    }
    #pragma unroll
    for (int j = 0; j < 8; ++j) Tl[t][j] = Tr[j];
    __syncthreads();

    const int i = t >> 3, j = t & 7;
    float st = 0.f;
    for (int a = 0; a < 64; ++a) st = fmaf(Wg[a * 8 + i], Tl[a][j], st);
    STl[t] = st;
    __syncthreads();

    float mx = STl[i * 8];
    #pragma unroll
    for (int jj = 1; jj < 8; ++jj) mx = fmaxf(mx, STl[i * 8 + jj]);
    float e = expf(st - mx);
    El[t] = e;
    __syncthreads();

    float den = 0.f;
    #pragma unroll
    for (int jj = 0; jj < 8; ++jj) den += El[i * 8 + jj];
    Bl[t] = e / den;
    __syncthreads();

    if (t < 8) {
        float u = 0.f;
        #pragma unroll
        for (int ii = 0; ii < 8; ++ii) u += Bl[ii * 8 + t] * Wv[ii];
        ul[t] = u;
    }
    __syncthreads();

    float wv = 0.f;
    #pragma unroll
    for (int jj = 0; jj < 8; ++jj) wv = fmaf(Wh[t * 8 + jj], ul[jj], wv);
    w_out[t] = wv * Gamma[0];
}

// ---------------- K3: fused V + output, 16 groups per block ----------------
// V phase: 1024 consecutive pixels (256 KB contiguous) -> vbuf[1024].
// Out phase: 64 segments of 16 rows = 4 KB contiguous read + NT write; the
// per-thread V float4 is loop-invariant.
__global__ __launch_bounds__(256) void k_vout(const float* __restrict__ x,
                                              const float* __restrict__ wvec,
                                              float* __restrict__ out) {
    __shared__ float vbuf[1024];
    __shared__ float wl[64];
    const int t = threadIdx.x;
    if (t < 64) wl[t] = wvec[t];
    __syncthreads();
    const int s = t >> 2, q = t & 3;
    float wreg[16];
    #pragma unroll
    for (int j = 0; j < 16; ++j) wreg[j] = wl[q * 16 + j];

    const int g0 = blockIdx.x * 16;       // grid 512
    // ---- V phase ----
    #pragma unroll 2
    for (int it = 0; it < 16; ++it) {
        const int pp = it * 64 + s;
        const float* src = x + ((size_t)g0 * 64 + pp) * 64 + q * 16;
        float part = 0.f;
        #pragma unroll
        for (int jj = 0; jj < 4; ++jj) {
            f32x4 v = *(const f32x4*)(src + jj * 4);
            part = fmaf(v[0], wreg[jj * 4 + 0], part);
            part = fmaf(v[1], wreg[jj * 4 + 1], part);
            part = fmaf(v[2], wreg[jj * 4 + 2], part);
            part = fmaf(v[3], wreg[jj * 4 + 3], part);
        }
        part += __shfl_xor(part, 1);
        part += __shfl_xor(part, 2);
        if (q == 0) vbuf[pp] = part;
    }
    __syncthreads();
    // ---- out phase ----
    const f32x4* x4 = (const f32x4*)x;
    f32x4* o4 = (f32x4*)out;
    const f32x4 vv = ((const f32x4*)vbuf)[t];   // row t>>4, chans 4*(t&15)
    #pragma unroll 4
    for (int s2 = 0; s2 < 64; ++s2) {
        const size_t base = ((size_t)(g0 + 8192 * s2)) * 16 + t;
        f32x4 a = x4[base];
        f32x4 r = a + vv;
        __builtin_nontemporal_store(r, &o4[base]);
    }
}

extern "C" void kernel_launch(void* const* d_in, const int* in_sizes, int n_in,
                              void* d_out, int out_size, void* d_ws, size_t ws_size,
                              hipStream_t stream) {
    const float* x     = (const float*)d_in[0];
    const float* Wf    = (const float*)d_in[1];
    const float* Wg    = (const float*)d_in[2];
    const float* Wh    = (const float*)d_in[3];
    const float* Wv    = (const float*)d_in[4];
    const float* Gamma = (const float*)d_in[5];
    float* out = (float*)d_out;

    float* M = (float*)d_ws;          // 4096 floats
    float* w = M + 4096;              // 64 floats

    hipMemsetAsync(M, 0, 4096 * sizeof(float), stream);
    hipLaunchKernelGGL(k_cov, dim3(COV_BLOCKS), dim3(256), 0, stream, x, M);
    hipLaunchKernelGGL(k_beta, dim3(1), dim3(64), 0, stream, M, Wf, Wg, Wh, Wv, Gamma, w);
    hipLaunchKernelGGL(k_vout, dim3(NGROUP / 16), dim3(256), 0, stream, x, w, out);
}